// Round 12
// baseline (525.317 us; speedup 1.0000x reference)
//
#include <hip/hip_runtime.h>

// T2ICrossAttentionPool on MI355X.
// Identities: w12[c,i,w] = sum_r attn*Sraw;  |wctx|^2 = a^T G a with
//   G = exact fp32 diag (register math) + off-diag G' bf16 (MFMA quadratic form).
// R13/R19: depth-3 reg K-loop, (256,3): ~433us. R14-R18: staging CLOSED (loses).
// R20: saddr neutral -> TA/latency-bound. R21: fat waves (1 cap x 2 img,
//   (256,2)): 412us. MfmaUtil 27.7 matches 128B/cy TA model; waves ~70%
//   stalled -> latency exposure at 2 waves/SIMD, concentrated in epilogue.
// R22: per-image attn LDS slices (attn[4][2][4096] = 64KB exactly). The two
//   epilogues previously serialized on the shared attn buffer (WAR: im=1
//   writes vs im=0 af reads). Disjoint slices -> compiler interleaves both
//   chains (2x ILP in the latency-bound region). w12/w2d/w2x LDS arrays
//   replaced by registers + shfl-select in final (post-butterfly, every lane
//   holds the reduced values; lane=w -> mt=quad, src lane=l15).

#define NIMG 256
#define NREG 36
#define DIM 1024
#define NCAP 256
#define MAXW 60
#define WPAD 64

typedef short bf16x8 __attribute__((ext_vector_type(8)));
typedef float f32x4 __attribute__((ext_vector_type(4)));

__device__ __forceinline__ unsigned short f2bf(float f) {
  unsigned u = __float_as_uint(f);
  u += 0x7FFF + ((u >> 16) & 1);   // round-to-nearest-even
  return (unsigned short)(u >> 16);
}

// ---- prep: caption permutation sorted by length (rank-count) + zero w1sq ----
// Zeroing here makes the caps_frag atomicAdd accumulation replay-idempotent.
__global__ void k_sort(const int* __restrict__ cap_lens, int* __restrict__ perm,
                       float* __restrict__ w1sq) {
  const int i = threadIdx.x;           // 256 threads
#pragma unroll
  for (int j = 0; j < WPAD; ++j) w1sq[i * WPAD + j] = 0.f;
  const int li = cap_lens[i];
  int r = 0;
  for (int j = 0; j < NCAP; ++j) {
    const int lj = cap_lens[j];
    r += (lj < li) || (lj == li && j < i);
  }
  perm[r] = i;
}

// ---- prep: caps -> fragments, masked (rows w>=clen zero); fused w1 partial ----
// Layout: qbfF[(((c*32 + k32)*4 + mt)*64 + lane)*8 + j]
//   = q[c][m = mt*16 + (lane&15)][k = k32*32 + (lane>>4)*8 + j]
// w1sq[c][m] += sum_k(q^2) over this block's 32-k slice (fp32, pre-bf16).
__global__ void k_prep_caps_frag(const float* __restrict__ caps, const int* __restrict__ cap_lens,
                                 unsigned short* __restrict__ qbfF,
                                 float* __restrict__ w1sq) {
  const int k32 = blockIdx.x;
  const int c = blockIdx.y;
  const int t = threadIdx.x;
  const int mt = t >> 6;
  const int lane = t & 63;
  const int m = mt * 16 + (lane & 15);
  const int k0 = k32 * 32 + (lane >> 4) * 8;
  const int clen = cap_lens[c];
  float4 v0 = make_float4(0.f, 0.f, 0.f, 0.f), v1 = v0;
  if (m < clen && m < MAXW) {
    const float* src = caps + ((size_t)c * MAXW + m) * DIM + k0;
    v0 = *reinterpret_cast<const float4*>(src);
    v1 = *reinterpret_cast<const float4*>(src + 4);
  }
  float ss = v0.x * v0.x + v0.y * v0.y + v0.z * v0.z + v0.w * v0.w
           + v1.x * v1.x + v1.y * v1.y + v1.z * v1.z + v1.w * v1.w;
  ss += __shfl_xor(ss, 16);
  ss += __shfl_xor(ss, 32);
  if ((lane >> 4) == 0 && ss != 0.f) atomicAdd(&w1sq[(size_t)c * WPAD + m], ss);
  ushort4 o0, o1;
  o0.x = f2bf(v0.x); o0.y = f2bf(v0.y); o0.z = f2bf(v0.z); o0.w = f2bf(v0.w);
  o1.x = f2bf(v1.x); o1.y = f2bf(v1.y); o1.z = f2bf(v1.z); o1.w = f2bf(v1.w);
  unsigned short* dst = qbfF + ((size_t)(((c * 32 + k32) * 4 + mt) * 64 + lane)) * 8;
  *reinterpret_cast<ushort4*>(dst) = o0;
  *reinterpret_cast<ushort4*>(dst + 4) = o1;
}

// ---- prep: imgs -> fragments (rows r>=36 zero) ----
// Layout: ibfF[(((i*32 + k32)*3 + nt)*64 + lane)*8 + j]
//   = imgs[i][r = nt*16 + (lane&15)][k = k32*32 + (lane>>4)*8 + j]
__global__ void k_prep_imgs_frag(const float* __restrict__ imgs,
                                 unsigned short* __restrict__ ibfF) {
  const int k32 = blockIdx.x;
  const int i = blockIdx.y;
  const int t = threadIdx.x;          // 0..191
  const int nt = t >> 6;
  const int lane = t & 63;
  const int r = nt * 16 + (lane & 15);
  const int k0 = k32 * 32 + (lane >> 4) * 8;
  float4 v0 = make_float4(0.f, 0.f, 0.f, 0.f), v1 = v0;
  if (r < NREG) {
    const float* src = imgs + ((size_t)i * NREG + r) * DIM + k0;
    v0 = *reinterpret_cast<const float4*>(src);
    v1 = *reinterpret_cast<const float4*>(src + 4);
  }
  ushort4 o0, o1;
  o0.x = f2bf(v0.x); o0.y = f2bf(v0.y); o0.z = f2bf(v0.z); o0.w = f2bf(v0.w);
  o1.x = f2bf(v1.x); o1.y = f2bf(v1.y); o1.z = f2bf(v1.z); o1.w = f2bf(v1.w);
  unsigned short* dst = ibfF + ((size_t)(((i * 32 + k32) * 3 + nt) * 64 + lane)) * 8;
  *reinterpret_cast<ushort4*>(dst) = o0;
  *reinterpret_cast<ushort4*>(dst + 4) = o1;
}

// ---- Gram via MFMA: one wave per image (same ibfF line feeds both operands) ----
__global__ void k_gram_mfma(const float* __restrict__ imgs,
                            const unsigned short* __restrict__ ibfF,
                            unsigned short* __restrict__ gbf,
                            float* __restrict__ gdiag) {
  const int i = blockIdx.x;
  const int lane = threadIdx.x & 63;
  const int l15 = lane & 15;
  const int quad = lane >> 4;

  // exact fp32 diag: rows r0+quad, k split across the 16 lanes of each quad
  float* dg = gdiag + (size_t)i * 48;
#pragma unroll
  for (int r0 = 0; r0 < 36; r0 += 4) {
    const int r = r0 + quad;
    const float* row = imgs + ((size_t)i * NREG + r) * DIM;
    float ss = 0.f;
#pragma unroll
    for (int p = 0; p < 16; ++p) {
      float4 v = *reinterpret_cast<const float4*>(row + p * 64 + l15 * 4);
      ss += v.x * v.x + v.y * v.y + v.z * v.z + v.w * v.w;
    }
    ss += __shfl_xor(ss, 1); ss += __shfl_xor(ss, 2);
    ss += __shfl_xor(ss, 4); ss += __shfl_xor(ss, 8);
    if (l15 == 0) dg[r] = ss;
  }
  if (lane < 12) dg[36 + lane] = 0.f;

  const unsigned short* base = ibfF + ((size_t)i * 32 * 3) * 512 + lane * 8;
  const f32x4 zero4 = {0.f, 0.f, 0.f, 0.f};
  f32x4 acc[3][3];
#pragma unroll
  for (int na = 0; na < 3; ++na)
#pragma unroll
    for (int nb = 0; nb < 3; ++nb) acc[na][nb] = zero4;
  bf16x8 f[2][3];
#pragma unroll
  for (int nt = 0; nt < 3; ++nt)
    f[0][nt] = *reinterpret_cast<const bf16x8*>(base + (size_t)nt * 512);
#pragma unroll
  for (int k32 = 0; k32 < 32; ++k32) {
    if (k32 + 1 < 32) {
      const int nb_ = (k32 + 1) & 1;
#pragma unroll
      for (int nt = 0; nt < 3; ++nt)
        f[nb_][nt] = *reinterpret_cast<const bf16x8*>(base + ((size_t)(k32 + 1) * 3 + nt) * 512);
    }
    const int b = k32 & 1;
#pragma unroll
    for (int na = 0; na < 3; ++na)
#pragma unroll
      for (int nb = 0; nb < 3; ++nb)
        acc[na][nb] = __builtin_amdgcn_mfma_f32_16x16x32_bf16(f[b][na], f[b][nb], acc[na][nb], 0, 0, 0);
  }
  unsigned short* g = gbf + (size_t)i * (48 * 64);
#pragma unroll
  for (int na = 0; na < 3; ++na)
#pragma unroll
    for (int nb = 0; nb < 3; ++nb)
#pragma unroll
      for (int rg = 0; rg < 4; ++rg) {
        const int r = na * 16 + quad * 4 + rg;   // C row
        const int c = nb * 16 + l15;             // C col
        g[r * 64 + c] = (r == c) ? (unsigned short)0 : f2bf(acc[na][nb][rg]);
      }
  // zero the K-pad cols 48..63 (16 ushorts = 2 uint4 per row)
  for (int idx = lane; idx < 96; idx += 64) {
    const int r = idx >> 1, half = idx & 1;
    *reinterpret_cast<uint4*>(g + r * 64 + 48 + half * 8) = make_uint4(0, 0, 0, 0);
  }
}

// ---- K-loop: 1 cap x 2 img fat wave, depth-2 register pipeline ----
// A (cap) fragments loaded ONCE, feed MFMAs for BOTH images: loads/k32 =
// MLIM+6 for 6*MLIM MFMAs. acc[im][nt][mt].
template <int MLIM>
__device__ __forceinline__ void kloopT2(const unsigned short* __restrict__ aBase,  // cap, uniform
                                        const unsigned short* __restrict__ bBase,  // img0, uniform
                                        const int lane8,
                                        f32x4 (&acc)[2][3][4]) {
  bf16x8 fa[2][MLIM], fb[2][2][3];
  auto load = [&](int k32, int buf) __attribute__((always_inline)) {
#pragma unroll
    for (int im = 0; im < 2; ++im)
#pragma unroll
      for (int nt = 0; nt < 3; ++nt)
        fb[buf][im][nt] = *reinterpret_cast<const bf16x8*>(
            bBase + (size_t)im * (32 * 3 * 512) + (size_t)k32 * 1536 + nt * 512 + lane8);
#pragma unroll
    for (int mt = 0; mt < MLIM; ++mt)
      fa[buf][mt] = *reinterpret_cast<const bf16x8*>(aBase + (size_t)k32 * 2048 + mt * 512 + lane8);
  };
  auto compute = [&](int buf) __attribute__((always_inline)) {
#pragma unroll
    for (int im = 0; im < 2; ++im)
#pragma unroll
      for (int mt = 0; mt < MLIM; ++mt)
#pragma unroll
        for (int nt = 0; nt < 3; ++nt)
          acc[im][nt][mt] = __builtin_amdgcn_mfma_f32_16x16x32_bf16(
              fb[buf][im][nt], fa[buf][mt], acc[im][nt][mt], 0, 0, 0);
  };
  load(0, 0);
#pragma unroll
  for (int k32 = 0; k32 < 32; ++k32) {
    if (k32 + 1 < 32) load(k32 + 1, (k32 + 1) & 1);
    __builtin_amdgcn_sched_barrier(0);   // pin: prefetch issued above, MFMAs stay below
    compute(k32 & 1);
  }
}

// ---- main fused kernel ----
// Grid (I/4, C/2), block 256 = 4 waves: wave wv -> (cap wv&1 of sorted pair,
// imgs i0+2*(wv>>1) .. +1). XCD swizzle: each XCD owns an 8-wide bx stripe.
__launch_bounds__(256, 2)
__global__ void k_main(const unsigned short* __restrict__ qbfF,
                       const unsigned short* __restrict__ ibfF,
                       const float* __restrict__ w1sq,
                       const unsigned short* __restrict__ gbf,
                       const float* __restrict__ gdiag,
                       const int* __restrict__ cap_lens,
                       const int* __restrict__ perm,
                       float* __restrict__ out) {
  __shared__ struct {
    unsigned short attn[4][2][4096];  // bf16 [w][r] per (wave, image); XOR-swizzled
  } lds;                               // 65536 B exactly -> 2 blocks/CU
  const int tid = threadIdx.x;
  const int lane = tid & 63;
  const int wv = tid >> 6;
  const int l15 = lane & 15;
  const int quad = lane >> 4;
  // ---- XCD-aware swizzle (8192 blocks, %8==0 -> bijective) ----
  const int flat = blockIdx.y * (NIMG / 4) + blockIdx.x;
  const int xcd = flat & 7;
  const int idx = flat >> 3;
  const int bx = xcd * 8 + (idx & 7);
  const int by = idx >> 3;
  const int i0 = bx * 4;
  const int cA = perm[2 * by], cB = perm[2 * by + 1];
  // wave-uniform (readfirstlane proves it to divergence analysis)
  const int c = __builtin_amdgcn_readfirstlane((wv & 1) ? cB : cA);
  const int imgBase = __builtin_amdgcn_readfirstlane(i0 + (wv >> 1) * 2);
  const int clen = cap_lens[c];
  const int mlim = __builtin_amdgcn_readfirstlane((clen + 15) >> 4);   // 1..4 valid w-tiles

  f32x4 acc[2][3][4];
  const f32x4 zero4 = {0.f, 0.f, 0.f, 0.f};
#pragma unroll
  for (int im = 0; im < 2; ++im)
#pragma unroll
    for (int nt = 0; nt < 3; ++nt)
#pragma unroll
      for (int mt = 0; mt < 4; ++mt) acc[im][nt][mt] = zero4;

  const unsigned short* aBase = qbfF + (size_t)c * (32 * 4 * 512);        // uniform
  const unsigned short* bBase = ibfF + (size_t)imgBase * (32 * 3 * 512);  // uniform
  const int lane8 = lane * 8;

  switch (mlim) {
    case 1: kloopT2<1>(aBase, bBase, lane8, acc); break;
    case 2: kloopT2<2>(aBase, bBase, lane8, acc); break;
    case 3: kloopT2<3>(aBase, bBase, lane8, acc); break;
    default: kloopT2<4>(aBase, bBase, lane8, acc); break;
  }

  // ---- epilogue (wave-private LDS; per-IMAGE slices -> the two image
  // epilogues are provably independent and can interleave) ----
  {
    // zero both image slices (8192 ushorts = 1024 uint4); pad groups
    // {6^key,7^key} per row must read 0 in the Yt phase.
    uint4* ab = reinterpret_cast<uint4*>(&lds.attn[wv][0][0]);
    const uint4 z4 = make_uint4(0, 0, 0, 0);
    for (int j = lane; j < 1024; j += 64) ab[j] = z4;
  }
  const float* w1Base = w1sq + (size_t)c * WPAD;   // uniform

#pragma unroll
  for (int im = 0; im < 2; ++im) {
    const int img = imgBase + im;
    // exact diag per register row r = nt*16 + quad*4 + rg
    const float* dg = gdiag + (size_t)img * 48;    // uniform base
    float dv[3][4];
#pragma unroll
    for (int nt = 0; nt < 3; ++nt)
#pragma unroll
      for (int rg = 0; rg < 4; ++rg)
        dv[nt][rg] = dg[nt * 16 + quad * 4 + rg];

    // pass 1: per-region l2 norm over w -> scale (in-reg over mt, then xor1..8)
    float scale[3][4];
#pragma unroll
    for (int nt = 0; nt < 3; ++nt)
#pragma unroll
      for (int rg = 0; rg < 4; ++rg) {
        float p = 0.f;
#pragma unroll
        for (int mt = 0; mt < 4; ++mt)
          if (mt < mlim) {
            const float s = acc[im][nt][mt][rg];
            const float l = s < 0.f ? 0.1f * s : s;
            p += l * l;
          }
        p += __shfl_xor(p, 1); p += __shfl_xor(p, 2);
        p += __shfl_xor(p, 4); p += __shfl_xor(p, 8);
        scale[nt][rg] = 9.0f / (sqrtf(p) + 1e-8f);   // SMOOTH folded in
      }

    // pass 2: softmax over r per w-column. |t| <= 9 -> no max subtraction.
    // Invalid r (>=36): nt==2 && quad!=0 -> e=0. Normalized attn packed as
    // bf16 pairs (bit-identical to the LDS attn values). Post-butterfly, ALL
    // lanes hold the reduced w12/w2d values -> keep in registers (no LDS).
    unsigned a_pk[4][3][2];
    float w12r[4] = {0.f, 0.f, 0.f, 0.f};
    float w2dr[4] = {0.f, 0.f, 0.f, 0.f};
    float w2xr[4] = {0.f, 0.f, 0.f, 0.f};
#pragma unroll
    for (int mt = 0; mt < 4; ++mt) {
      if (mt >= mlim) continue;
      float ee[3][4];
      float sm = 0.f, wp = 0.f, dd = 0.f;
#pragma unroll
      for (int nt = 0; nt < 3; ++nt) {
        const bool rvalid = (nt < 2) || (quad == 0);
#pragma unroll
        for (int rg = 0; rg < 4; ++rg) {
          const float s = acc[im][nt][mt][rg];
          const float l = s < 0.f ? 0.1f * s : s;
          const float e0 = rvalid ? __expf(l * scale[nt][rg]) : 0.f;
          ee[nt][rg] = e0;
          sm += e0;
          wp += e0 * s;                       // w12 uses RAW s
          dd += e0 * e0 * dv[nt][rg];         // exact diag term
        }
      }
      sm += __shfl_xor(sm, 16); sm += __shfl_xor(sm, 32);
      wp += __shfl_xor(wp, 16); wp += __shfl_xor(wp, 32);
      dd += __shfl_xor(dd, 16); dd += __shfl_xor(dd, 32);
      const float inv = 1.0f / sm;
      w12r[mt] = wp * inv;
      w2dr[mt] = dd * inv * inv;
      const int w = mt * 16 + l15;
      const int key = l15 & 7;
      unsigned short* arow = &lds.attn[wv][im][w * 64];
#pragma unroll
      for (int nt = 0; nt < 3; ++nt)
#pragma unroll
        for (int pr = 0; pr < 2; ++pr) {
          const unsigned b0 = f2bf(ee[nt][2 * pr] * inv);
          const unsigned b1 = f2bf(ee[nt][2 * pr + 1] * inv);
          const unsigned pk = b0 | (b1 << 16);
          a_pk[mt][nt][pr] = pk;
          // r0 even, r1 = r0+1: same 8-group, adjacent -> one aligned u32 store
          const int r0 = nt * 16 + quad * 4 + 2 * pr;
          *reinterpret_cast<unsigned*>(&arow[(((r0 >> 3) ^ key) << 3) + (r0 & 7)]) = pk;
        }
    }

    // Yt = G x Attn^T via MFMA -> Yt[nt][rg] in the a_pk register layout.
    const unsigned short* gBase = gbf + (size_t)img * (48 * 64);   // uniform
    bf16x8 gfrag[3][2];
#pragma unroll
    for (int nt = 0; nt < 3; ++nt)
#pragma unroll
      for (int ks = 0; ks < 2; ++ks)
        gfrag[nt][ks] = *reinterpret_cast<const bf16x8*>(
            gBase + (nt * 16 + l15) * 64 + ((ks * 4 + quad) << 3));
#pragma unroll
    for (int mt = 0; mt < 4; ++mt) {
      if (mt >= mlim) continue;
      bf16x8 af[2];
#pragma unroll
      for (int ks = 0; ks < 2; ++ks)
        af[ks] = *reinterpret_cast<const bf16x8*>(
            &lds.attn[wv][im][(mt * 16 + l15) * 64 + (((ks * 4 + quad) ^ (l15 & 7)) << 3)]);
      f32x4 Yt[3] = {zero4, zero4, zero4};
#pragma unroll
      for (int nt = 0; nt < 3; ++nt)
#pragma unroll
        for (int ks = 0; ks < 2; ++ks)
          Yt[nt] = __builtin_amdgcn_mfma_f32_16x16x32_bf16(gfrag[nt][ks], af[ks], Yt[nt], 0, 0, 0);
      // cross term: w2x[w] = sum_r a[w][r] * Y[r][w]; a unpacked from bf16 pairs
      float p = 0.f;
#pragma unroll
      for (int nt = 0; nt < 3; ++nt)
#pragma unroll
        for (int pr = 0; pr < 2; ++pr) {
          const unsigned pk = a_pk[mt][nt][pr];
          const float a0 = __uint_as_float(pk << 16);
          const float a1 = __uint_as_float(pk & 0xffff0000u);
          p += a0 * Yt[nt][2 * pr] + a1 * Yt[nt][2 * pr + 1];
        }
      p += __shfl_xor(p, 16); p += __shfl_xor(p, 32);
      w2xr[mt] = p;   // all lanes hold it post-butterfly
    }

    // final: lane = w. Value for w lives in register slot mt=w>>4=quad of
    // any lane with l15 == w&15 -> 4 shfl + quad-select per quantity.
    {
      const float q0 = __shfl(w12r[0], l15), q1 = __shfl(w12r[1], l15);
      const float q2 = __shfl(w12r[2], l15), q3 = __shfl(w12r[3], l15);
      const float w12v = quad == 0 ? q0 : quad == 1 ? q1 : quad == 2 ? q2 : q3;
      const float d0 = __shfl(w2dr[0], l15), d1 = __shfl(w2dr[1], l15);
      const float d2 = __shfl(w2dr[2], l15), d3 = __shfl(w2dr[3], l15);
      const float w2dv = quad == 0 ? d0 : quad == 1 ? d1 : quad == 2 ? d2 : d3;
      const float x0 = __shfl(w2xr[0], l15), x1 = __shfl(w2xr[1], l15);
      const float x2 = __shfl(w2xr[2], l15), x3 = __shfl(w2xr[3], l15);
      const float w2xv = quad == 0 ? x0 : quad == 1 ? x1 : quad == 2 ? x2 : x3;
      float simv = 0.f;
      if (lane < clen) {
        const float w2sq = fmaxf(w2xv + w2dv, 0.f);
        const float w2v = sqrtf(w2sq);
        const float w1v = sqrtf(w1Base[lane]);
        simv = w12v / fmaxf(w1v * w2v, 1e-8f);
      }
      simv += __shfl_xor(simv, 1);
      simv += __shfl_xor(simv, 2);
      simv += __shfl_xor(simv, 4);
      simv += __shfl_xor(simv, 8);
      simv += __shfl_xor(simv, 16);
      simv += __shfl_xor(simv, 32);
      if (lane == 0) out[(size_t)img * NCAP + c] = simv / (float)clen;
    }
  }
}

extern "C" void kernel_launch(void* const* d_in, const int* in_sizes, int n_in,
                              void* d_out, int out_size, void* d_ws, size_t ws_size,
                              hipStream_t stream) {
  const float* imgs = (const float*)d_in[0];
  const float* caps = (const float*)d_in[1];
  const int* cap_lens = (const int*)d_in[3];   // img_lens (d_in[2]) unused by reference
  float* out = (float*)d_out;

  char* ws = (char*)d_ws;
  const size_t QBF_B = (size_t)NCAP * 32 * 4 * 512 * 2;      // 33,554,432
  const size_t IBF_B = (size_t)NIMG * 32 * 3 * 512 * 2;      // 25,165,824
  const size_t W1_B = (size_t)NCAP * WPAD * 4;               // 65,536
  const size_t GBF_B = (size_t)NIMG * 48 * 64 * 2;           // 1,572,864
  const size_t GD_B = (size_t)NIMG * 48 * 4;                 // 49,152
  unsigned short* qbfF = (unsigned short*)ws;
  unsigned short* ibfF = (unsigned short*)(ws + QBF_B);
  float* w1sq = (float*)(ws + QBF_B + IBF_B);
  unsigned short* gbf = (unsigned short*)(ws + QBF_B + IBF_B + W1_B);
  float* gdiag = (float*)(ws + QBF_B + IBF_B + W1_B + GBF_B);
  int* perm = (int*)(ws + QBF_B + IBF_B + W1_B + GBF_B + GD_B);

  k_sort<<<1, NCAP, 0, stream>>>(cap_lens, perm, w1sq);
  k_prep_caps_frag<<<dim3(32, NCAP), 256, 0, stream>>>(caps, cap_lens, qbfF, w1sq);
  k_prep_imgs_frag<<<dim3(32, NIMG), 192, 0, stream>>>(imgs, ibfF);
  k_gram_mfma<<<NIMG, 64, 0, stream>>>(imgs, ibfF, gbf, gdiag);
  k_main<<<dim3(NIMG / 4, NCAP / 2), 256, 0, stream>>>(qbfF, ibfF, w1sq, gbf, gdiag, cap_lens, perm, out);
}

// Round 13
// 515.843 us; speedup vs baseline: 1.0184x; 1.0184x over previous
//
#include <hip/hip_runtime.h>

// T2ICrossAttentionPool on MI355X.
// Identities: w12[c,i,w] = sum_r attn*Sraw;  |wctx|^2 = a^T G a with
//   G = exact fp32 diag (register math) + off-diag G' bf16 (MFMA quadratic form).
// R13/R19: depth-3 reg K-loop, (256,3): ~433us. R14-R18: staging CLOSED.
// R20: saddr neutral. R21 (BEST, 412us): fat waves 1 cap x 2 img, (256,2).
// R22: per-image attn slices REGRESSED (-3%): epilogue serialization is
//   register-forced, not LDS-forced; paid 2x zeroing on 64KB LDS. Reverted.
// R23: R21 base + (1) v_cvt_pk_bf16_f32 packs attention-weight pairs in 1
//   instr vs ~9 manual-RNE VALU ops (~630 VALU/wave saved; NOT the m240
//   anti-pattern - replaces hand bit-twiddle, not a compiler cast) +
//   (2) T5 s_setprio around K-loop MFMA cluster (barrier-free independent
//   waves = the m191-positive regime).

#define NIMG 256
#define NREG 36
#define DIM 1024
#define NCAP 256
#define MAXW 60
#define WPAD 64

typedef short bf16x8 __attribute__((ext_vector_type(8)));
typedef float f32x4 __attribute__((ext_vector_type(4)));

__device__ __forceinline__ unsigned short f2bf(float f) {
  unsigned u = __float_as_uint(f);
  u += 0x7FFF + ((u >> 16) & 1);   // round-to-nearest-even
  return (unsigned short)(u >> 16);
}

// packed fp32x2 -> bf16x2 (RNE), low16 = a, high16 = b
__device__ __forceinline__ unsigned cvt_pk_bf16(float a, float b) {
  unsigned r;
  asm("v_cvt_pk_bf16_f32 %0, %1, %2" : "=v"(r) : "v"(a), "v"(b));
  return r;
}

// ---- prep: caption permutation sorted by length (rank-count) + zero w1sq ----
// Zeroing here makes the caps_frag atomicAdd accumulation replay-idempotent.
__global__ void k_sort(const int* __restrict__ cap_lens, int* __restrict__ perm,
                       float* __restrict__ w1sq) {
  const int i = threadIdx.x;           // 256 threads
#pragma unroll
  for (int j = 0; j < WPAD; ++j) w1sq[i * WPAD + j] = 0.f;
  const int li = cap_lens[i];
  int r = 0;
  for (int j = 0; j < NCAP; ++j) {
    const int lj = cap_lens[j];
    r += (lj < li) || (lj == li && j < i);
  }
  perm[r] = i;
}

// ---- prep: caps -> fragments, masked (rows w>=clen zero); fused w1 partial ----
// Layout: qbfF[(((c*32 + k32)*4 + mt)*64 + lane)*8 + j]
//   = q[c][m = mt*16 + (lane&15)][k = k32*32 + (lane>>4)*8 + j]
// w1sq[c][m] += sum_k(q^2) over this block's 32-k slice (fp32, pre-bf16).
__global__ void k_prep_caps_frag(const float* __restrict__ caps, const int* __restrict__ cap_lens,
                                 unsigned short* __restrict__ qbfF,
                                 float* __restrict__ w1sq) {
  const int k32 = blockIdx.x;
  const int c = blockIdx.y;
  const int t = threadIdx.x;
  const int mt = t >> 6;
  const int lane = t & 63;
  const int m = mt * 16 + (lane & 15);
  const int k0 = k32 * 32 + (lane >> 4) * 8;
  const int clen = cap_lens[c];
  float4 v0 = make_float4(0.f, 0.f, 0.f, 0.f), v1 = v0;
  if (m < clen && m < MAXW) {
    const float* src = caps + ((size_t)c * MAXW + m) * DIM + k0;
    v0 = *reinterpret_cast<const float4*>(src);
    v1 = *reinterpret_cast<const float4*>(src + 4);
  }
  float ss = v0.x * v0.x + v0.y * v0.y + v0.z * v0.z + v0.w * v0.w
           + v1.x * v1.x + v1.y * v1.y + v1.z * v1.z + v1.w * v1.w;
  ss += __shfl_xor(ss, 16);
  ss += __shfl_xor(ss, 32);
  if ((lane >> 4) == 0 && ss != 0.f) atomicAdd(&w1sq[(size_t)c * WPAD + m], ss);
  ushort4 o0, o1;
  o0.x = f2bf(v0.x); o0.y = f2bf(v0.y); o0.z = f2bf(v0.z); o0.w = f2bf(v0.w);
  o1.x = f2bf(v1.x); o1.y = f2bf(v1.y); o1.z = f2bf(v1.z); o1.w = f2bf(v1.w);
  unsigned short* dst = qbfF + ((size_t)(((c * 32 + k32) * 4 + mt) * 64 + lane)) * 8;
  *reinterpret_cast<ushort4*>(dst) = o0;
  *reinterpret_cast<ushort4*>(dst + 4) = o1;
}

// ---- prep: imgs -> fragments (rows r>=36 zero) ----
// Layout: ibfF[(((i*32 + k32)*3 + nt)*64 + lane)*8 + j]
//   = imgs[i][r = nt*16 + (lane&15)][k = k32*32 + (lane>>4)*8 + j]
__global__ void k_prep_imgs_frag(const float* __restrict__ imgs,
                                 unsigned short* __restrict__ ibfF) {
  const int k32 = blockIdx.x;
  const int i = blockIdx.y;
  const int t = threadIdx.x;          // 0..191
  const int nt = t >> 6;
  const int lane = t & 63;
  const int r = nt * 16 + (lane & 15);
  const int k0 = k32 * 32 + (lane >> 4) * 8;
  float4 v0 = make_float4(0.f, 0.f, 0.f, 0.f), v1 = v0;
  if (r < NREG) {
    const float* src = imgs + ((size_t)i * NREG + r) * DIM + k0;
    v0 = *reinterpret_cast<const float4*>(src);
    v1 = *reinterpret_cast<const float4*>(src + 4);
  }
  ushort4 o0, o1;
  o0.x = f2bf(v0.x); o0.y = f2bf(v0.y); o0.z = f2bf(v0.z); o0.w = f2bf(v0.w);
  o1.x = f2bf(v1.x); o1.y = f2bf(v1.y); o1.z = f2bf(v1.z); o1.w = f2bf(v1.w);
  unsigned short* dst = ibfF + ((size_t)(((i * 32 + k32) * 3 + nt) * 64 + lane)) * 8;
  *reinterpret_cast<ushort4*>(dst) = o0;
  *reinterpret_cast<ushort4*>(dst + 4) = o1;
}

// ---- Gram via MFMA: one wave per image (same ibfF line feeds both operands) ----
__global__ void k_gram_mfma(const float* __restrict__ imgs,
                            const unsigned short* __restrict__ ibfF,
                            unsigned short* __restrict__ gbf,
                            float* __restrict__ gdiag) {
  const int i = blockIdx.x;
  const int lane = threadIdx.x & 63;
  const int l15 = lane & 15;
  const int quad = lane >> 4;

  // exact fp32 diag: rows r0+quad, k split across the 16 lanes of each quad
  float* dg = gdiag + (size_t)i * 48;
#pragma unroll
  for (int r0 = 0; r0 < 36; r0 += 4) {
    const int r = r0 + quad;
    const float* row = imgs + ((size_t)i * NREG + r) * DIM;
    float ss = 0.f;
#pragma unroll
    for (int p = 0; p < 16; ++p) {
      float4 v = *reinterpret_cast<const float4*>(row + p * 64 + l15 * 4);
      ss += v.x * v.x + v.y * v.y + v.z * v.z + v.w * v.w;
    }
    ss += __shfl_xor(ss, 1); ss += __shfl_xor(ss, 2);
    ss += __shfl_xor(ss, 4); ss += __shfl_xor(ss, 8);
    if (l15 == 0) dg[r] = ss;
  }
  if (lane < 12) dg[36 + lane] = 0.f;

  const unsigned short* base = ibfF + ((size_t)i * 32 * 3) * 512 + lane * 8;
  const f32x4 zero4 = {0.f, 0.f, 0.f, 0.f};
  f32x4 acc[3][3];
#pragma unroll
  for (int na = 0; na < 3; ++na)
#pragma unroll
    for (int nb = 0; nb < 3; ++nb) acc[na][nb] = zero4;
  bf16x8 f[2][3];
#pragma unroll
  for (int nt = 0; nt < 3; ++nt)
    f[0][nt] = *reinterpret_cast<const bf16x8*>(base + (size_t)nt * 512);
#pragma unroll
  for (int k32 = 0; k32 < 32; ++k32) {
    if (k32 + 1 < 32) {
      const int nb_ = (k32 + 1) & 1;
#pragma unroll
      for (int nt = 0; nt < 3; ++nt)
        f[nb_][nt] = *reinterpret_cast<const bf16x8*>(base + ((size_t)(k32 + 1) * 3 + nt) * 512);
    }
    const int b = k32 & 1;
#pragma unroll
    for (int na = 0; na < 3; ++na)
#pragma unroll
      for (int nb = 0; nb < 3; ++nb)
        acc[na][nb] = __builtin_amdgcn_mfma_f32_16x16x32_bf16(f[b][na], f[b][nb], acc[na][nb], 0, 0, 0);
  }
  unsigned short* g = gbf + (size_t)i * (48 * 64);
#pragma unroll
  for (int na = 0; na < 3; ++na)
#pragma unroll
    for (int nb = 0; nb < 3; ++nb)
#pragma unroll
      for (int rg = 0; rg < 4; ++rg) {
        const int r = na * 16 + quad * 4 + rg;   // C row
        const int c = nb * 16 + l15;             // C col
        g[r * 64 + c] = (r == c) ? (unsigned short)0 : f2bf(acc[na][nb][rg]);
      }
  // zero the K-pad cols 48..63 (16 ushorts = 2 uint4 per row)
  for (int idx = lane; idx < 96; idx += 64) {
    const int r = idx >> 1, half = idx & 1;
    *reinterpret_cast<uint4*>(g + r * 64 + 48 + half * 8) = make_uint4(0, 0, 0, 0);
  }
}

// ---- K-loop: 1 cap x 2 img fat wave, depth-2 register pipeline ----
// A (cap) fragments loaded ONCE, feed MFMAs for BOTH images: loads/k32 =
// MLIM+6 for 6*MLIM MFMAs. acc[im][nt][mt]. setprio(1) wraps the MFMA
// cluster (T5; barrier-free independent waves = the positive regime).
template <int MLIM>
__device__ __forceinline__ void kloopT2(const unsigned short* __restrict__ aBase,  // cap, uniform
                                        const unsigned short* __restrict__ bBase,  // img0, uniform
                                        const int lane8,
                                        f32x4 (&acc)[2][3][4]) {
  bf16x8 fa[2][MLIM], fb[2][2][3];
  auto load = [&](int k32, int buf) __attribute__((always_inline)) {
#pragma unroll
    for (int im = 0; im < 2; ++im)
#pragma unroll
      for (int nt = 0; nt < 3; ++nt)
        fb[buf][im][nt] = *reinterpret_cast<const bf16x8*>(
            bBase + (size_t)im * (32 * 3 * 512) + (size_t)k32 * 1536 + nt * 512 + lane8);
#pragma unroll
    for (int mt = 0; mt < MLIM; ++mt)
      fa[buf][mt] = *reinterpret_cast<const bf16x8*>(aBase + (size_t)k32 * 2048 + mt * 512 + lane8);
  };
  auto compute = [&](int buf) __attribute__((always_inline)) {
    __builtin_amdgcn_s_setprio(1);
#pragma unroll
    for (int im = 0; im < 2; ++im)
#pragma unroll
      for (int mt = 0; mt < MLIM; ++mt)
#pragma unroll
        for (int nt = 0; nt < 3; ++nt)
          acc[im][nt][mt] = __builtin_amdgcn_mfma_f32_16x16x32_bf16(
              fb[buf][im][nt], fa[buf][mt], acc[im][nt][mt], 0, 0, 0);
    __builtin_amdgcn_s_setprio(0);
  };
  load(0, 0);
#pragma unroll
  for (int k32 = 0; k32 < 32; ++k32) {
    if (k32 + 1 < 32) load(k32 + 1, (k32 + 1) & 1);
    __builtin_amdgcn_sched_barrier(0);   // pin: prefetch issued above, MFMAs stay below
    compute(k32 & 1);
  }
}

// ---- main fused kernel ----
// Grid (I/4, C/2), block 256 = 4 waves: wave wv -> (cap wv&1 of sorted pair,
// imgs i0+2*(wv>>1) .. +1). XCD swizzle: each XCD owns an 8-wide bx stripe
// (32 imgs, 3MB ibfF resident in its L2).
__launch_bounds__(256, 2)
__global__ void k_main(const unsigned short* __restrict__ qbfF,
                       const unsigned short* __restrict__ ibfF,
                       const float* __restrict__ w1sq,
                       const unsigned short* __restrict__ gbf,
                       const float* __restrict__ gdiag,
                       const int* __restrict__ cap_lens,
                       const int* __restrict__ perm,
                       float* __restrict__ out) {
  __shared__ struct {
    unsigned short attn[4][4096];     // bf16 [w][r], r-groups XOR-swizzled; reused per image
    float w12[4][64];
    float w2d[4][64];
    float w2x[4][64];
  } lds;                               // 35840 B -> 2 blocks/CU at (256,2)
  const int tid = threadIdx.x;
  const int lane = tid & 63;
  const int wv = tid >> 6;
  const int l15 = lane & 15;
  const int quad = lane >> 4;
  // ---- XCD-aware swizzle (8192 blocks, %8==0 -> bijective) ----
  const int flat = blockIdx.y * (NIMG / 4) + blockIdx.x;
  const int xcd = flat & 7;
  const int idx = flat >> 3;
  const int bx = xcd * 8 + (idx & 7);
  const int by = idx >> 3;
  const int i0 = bx * 4;
  const int cA = perm[2 * by], cB = perm[2 * by + 1];
  // wave-uniform (readfirstlane proves it to divergence analysis)
  const int c = __builtin_amdgcn_readfirstlane((wv & 1) ? cB : cA);
  const int imgBase = __builtin_amdgcn_readfirstlane(i0 + (wv >> 1) * 2);
  const int clen = cap_lens[c];
  const int mlim = __builtin_amdgcn_readfirstlane((clen + 15) >> 4);   // 1..4 valid w-tiles

  f32x4 acc[2][3][4];
  const f32x4 zero4 = {0.f, 0.f, 0.f, 0.f};
#pragma unroll
  for (int im = 0; im < 2; ++im)
#pragma unroll
    for (int nt = 0; nt < 3; ++nt)
#pragma unroll
      for (int mt = 0; mt < 4; ++mt) acc[im][nt][mt] = zero4;

  const unsigned short* aBase = qbfF + (size_t)c * (32 * 4 * 512);        // uniform
  const unsigned short* bBase = ibfF + (size_t)imgBase * (32 * 3 * 512);  // uniform
  const int lane8 = lane * 8;

  switch (mlim) {
    case 1: kloopT2<1>(aBase, bBase, lane8, acc); break;
    case 2: kloopT2<2>(aBase, bBase, lane8, acc); break;
    case 3: kloopT2<3>(aBase, bBase, lane8, acc); break;
    default: kloopT2<4>(aBase, bBase, lane8, acc); break;
  }

  // ---- epilogue (wave-private LDS; in-wave DS ordering suffices) ----
  // zero attn once; pass2 only ever writes groups {0..5}^key per row, so pad
  // groups stay 0 across both images; rows >= mlim*16 are never read.
  {
    uint4* ab = reinterpret_cast<uint4*>(&lds.attn[wv][0]);
    const uint4 z4 = make_uint4(0, 0, 0, 0);
    for (int j = lane; j < 512; j += 64) ab[j] = z4;
  }
  const float* w1Base = w1sq + (size_t)c * WPAD;   // uniform

#pragma unroll
  for (int im = 0; im < 2; ++im) {
    const int img = imgBase + im;
    // exact diag per register row r = nt*16 + quad*4 + rg
    const float* dg = gdiag + (size_t)img * 48;    // uniform base
    float dv[3][4];
#pragma unroll
    for (int nt = 0; nt < 3; ++nt)
#pragma unroll
      for (int rg = 0; rg < 4; ++rg)
        dv[nt][rg] = dg[nt * 16 + quad * 4 + rg];

    // pass 1: per-region l2 norm over w -> scale (in-reg over mt, then xor1..8)
    float scale[3][4];
#pragma unroll
    for (int nt = 0; nt < 3; ++nt)
#pragma unroll
      for (int rg = 0; rg < 4; ++rg) {
        float p = 0.f;
#pragma unroll
        for (int mt = 0; mt < 4; ++mt)
          if (mt < mlim) {
            const float s = acc[im][nt][mt][rg];
            const float l = s < 0.f ? 0.1f * s : s;
            p += l * l;
          }
        p += __shfl_xor(p, 1); p += __shfl_xor(p, 2);
        p += __shfl_xor(p, 4); p += __shfl_xor(p, 8);
        scale[nt][rg] = 9.0f / (sqrtf(p) + 1e-8f);   // SMOOTH folded in
      }

    // pass 2: softmax over r per w-column. |t| <= 9 -> no max subtraction.
    // Invalid r (>=36): nt==2 && quad!=0 -> e=0. Normalized attn packed as
    // bf16 pairs via v_cvt_pk_bf16_f32 (1 instr vs ~9 manual-RNE VALU ops),
    // bit-identical values in registers (a_pk) and LDS.
    unsigned a_pk[4][3][2];
#pragma unroll
    for (int mt = 0; mt < 4; ++mt) {
      if (mt >= mlim) continue;
      float ee[3][4];
      float sm = 0.f, wp = 0.f, dd = 0.f;
#pragma unroll
      for (int nt = 0; nt < 3; ++nt) {
        const bool rvalid = (nt < 2) || (quad == 0);
#pragma unroll
        for (int rg = 0; rg < 4; ++rg) {
          const float s = acc[im][nt][mt][rg];
          const float l = s < 0.f ? 0.1f * s : s;
          const float e0 = rvalid ? __expf(l * scale[nt][rg]) : 0.f;
          ee[nt][rg] = e0;
          sm += e0;
          wp += e0 * s;                       // w12 uses RAW s
          dd += e0 * e0 * dv[nt][rg];         // exact diag term
        }
      }
      sm += __shfl_xor(sm, 16); sm += __shfl_xor(sm, 32);
      wp += __shfl_xor(wp, 16); wp += __shfl_xor(wp, 32);
      dd += __shfl_xor(dd, 16); dd += __shfl_xor(dd, 32);
      const float inv = 1.0f / sm;
      const int w = mt * 16 + l15;
      const int key = l15 & 7;
      unsigned short* arow = &lds.attn[wv][w * 64];
#pragma unroll
      for (int nt = 0; nt < 3; ++nt)
#pragma unroll
        for (int pr = 0; pr < 2; ++pr) {
          const unsigned pk = cvt_pk_bf16(ee[nt][2 * pr] * inv, ee[nt][2 * pr + 1] * inv);
          a_pk[mt][nt][pr] = pk;
          // r0 even, r1 = r0+1: same 8-group, adjacent -> one aligned u32 store
          const int r0 = nt * 16 + quad * 4 + 2 * pr;
          *reinterpret_cast<unsigned*>(&arow[(((r0 >> 3) ^ key) << 3) + (r0 & 7)]) = pk;
        }
      if (quad == 0) { lds.w12[wv][w] = wp * inv; lds.w2d[wv][w] = dd * inv * inv; }
    }

    // Yt = G x Attn^T via MFMA -> Yt[nt][rg] in the a_pk register layout.
    const unsigned short* gBase = gbf + (size_t)img * (48 * 64);   // uniform
    bf16x8 gfrag[3][2];
#pragma unroll
    for (int nt = 0; nt < 3; ++nt)
#pragma unroll
      for (int ks = 0; ks < 2; ++ks)
        gfrag[nt][ks] = *reinterpret_cast<const bf16x8*>(
            gBase + (nt * 16 + l15) * 64 + ((ks * 4 + quad) << 3));
#pragma unroll
    for (int mt = 0; mt < 4; ++mt) {
      if (mt >= mlim) continue;
      bf16x8 af[2];
#pragma unroll
      for (int ks = 0; ks < 2; ++ks)
        af[ks] = *reinterpret_cast<const bf16x8*>(
            &lds.attn[wv][(mt * 16 + l15) * 64 + (((ks * 4 + quad) ^ (l15 & 7)) << 3)]);
      f32x4 Yt[3] = {zero4, zero4, zero4};
#pragma unroll
      for (int nt = 0; nt < 3; ++nt)
#pragma unroll
        for (int ks = 0; ks < 2; ++ks)
          Yt[nt] = __builtin_amdgcn_mfma_f32_16x16x32_bf16(gfrag[nt][ks], af[ks], Yt[nt], 0, 0, 0);
      // cross term: w2x[w] = sum_r a[w][r] * Y[r][w]; a unpacked from bf16 pairs
      float p = 0.f;
#pragma unroll
      for (int nt = 0; nt < 3; ++nt)
#pragma unroll
        for (int pr = 0; pr < 2; ++pr) {
          const unsigned pk = a_pk[mt][nt][pr];
          const float a0 = __uint_as_float(pk << 16);
          const float a1 = __uint_as_float(pk & 0xffff0000u);
          p += a0 * Yt[nt][2 * pr] + a1 * Yt[nt][2 * pr + 1];
        }
      p += __shfl_xor(p, 16); p += __shfl_xor(p, 32);
      if (quad == 0) lds.w2x[wv][mt * 16 + l15] = p;
    }

    // final: lane = word
    float simv = 0.f;
    if (lane < clen) {
      const float w2sq = fmaxf(lds.w2x[wv][lane] + lds.w2d[wv][lane], 0.f);
      const float w2v = sqrtf(w2sq);
      const float w12v = lds.w12[wv][lane];
      const float w1v = sqrtf(w1Base[lane]);
      simv = w12v / fmaxf(w1v * w2v, 1e-8f);
    }
    simv += __shfl_xor(simv, 1);
    simv += __shfl_xor(simv, 2);
    simv += __shfl_xor(simv, 4);
    simv += __shfl_xor(simv, 8);
    simv += __shfl_xor(simv, 16);
    simv += __shfl_xor(simv, 32);
    if (lane == 0) out[(size_t)img * NCAP + c] = simv / (float)clen;
  }
}

extern "C" void kernel_launch(void* const* d_in, const int* in_sizes, int n_in,
                              void* d_out, int out_size, void* d_ws, size_t ws_size,
                              hipStream_t stream) {
  const float* imgs = (const float*)d_in[0];
  const float* caps = (const float*)d_in[1];
  const int* cap_lens = (const int*)d_in[3];   // img_lens (d_in[2]) unused by reference
  float* out = (float*)d_out;

  char* ws = (char*)d_ws;
  const size_t QBF_B = (size_t)NCAP * 32 * 4 * 512 * 2;      // 33,554,432
  const size_t IBF_B = (size_t)NIMG * 32 * 3 * 512 * 2;      // 25,165,824
  const size_t W1_B = (size_t)NCAP * WPAD * 4;               // 65,536
  const size_t GBF_B = (size_t)NIMG * 48 * 64 * 2;           // 1,572,864
  const size_t GD_B = (size_t)NIMG * 48 * 4;                 // 49,152
  unsigned short* qbfF = (unsigned short*)ws;
  unsigned short* ibfF = (unsigned short*)(ws + QBF_B);
  float* w1sq = (float*)(ws + QBF_B + IBF_B);
  unsigned short* gbf = (unsigned short*)(ws + QBF_B + IBF_B + W1_B);
  float* gdiag = (float*)(ws + QBF_B + IBF_B + W1_B + GBF_B);
  int* perm = (int*)(ws + QBF_B + IBF_B + W1_B + GBF_B + GD_B);

  k_sort<<<1, NCAP, 0, stream>>>(cap_lens, perm, w1sq);
  k_prep_caps_frag<<<dim3(32, NCAP), 256, 0, stream>>>(caps, cap_lens, qbfF, w1sq);
  k_prep_imgs_frag<<<dim3(32, NIMG), 192, 0, stream>>>(imgs, ibfF);
  k_gram_mfma<<<NIMG, 64, 0, stream>>>(imgs, ibfF, gbf, gdiag);
  k_main<<<dim3(NIMG / 4, NCAP / 2), 256, 0, stream>>>(qbfF, ibfF, w1sq, gbf, gdiag, cap_lens, perm, out);
}